// Round 2
// baseline (290.751 us; speedup 1.0000x reference)
//
#include <hip/hip_runtime.h>

// Problem constants (mirror the reference)
#define EMB      200000
#define DIM      256
#define WALK     80
#define WIN      5
#define BATCH    32
#define PPW      770                 // positive pairs per walk: sum_i c(i)
#define NPOSN    (BATCH * PPW)       // 24640 positive pairs
#define NNEG     (NPOSN * 5)         // 123200 negative pairs
#define NPOSIT   (BATCH * WALK)      // 2560 node positions
#define LR       0.025f
#define LAP      0.01f
#define INV_STRIDE 64                // max 50 inverse hits per position

__device__ __forceinline__ float wave_sum(float s) {
#pragma unroll
    for (int off = 32; off > 0; off >>= 1) s += __shfl_xor(s, off, 64);
    return s;
}

__device__ __forceinline__ float fast_sig(const float* __restrict__ t, float d) {
    float s = fminf(fmaxf(d, -6.0f), 6.0f);
    int idx = (int)floorf((s + 6.01f) / 0.01f);
    return t[idx];
}

// Bulk table copy: out[0..T) = uw, out[T..2T) = vw.  blockIdx.y picks the table.
// Grid-stride float4 copy — the m13-verified ~6.3 TB/s pattern.
__global__ void __launch_bounds__(256) k_copy(const float* __restrict__ uw,
                                              const float* __restrict__ vw,
                                              float* __restrict__ out) {
    const size_t T4 = (size_t)EMB * DIM / 4;          // float4 per table
    const float4* __restrict__ src =
        (blockIdx.y == 0) ? (const float4*)uw : (const float4*)vw;
    float4* __restrict__ dst = (float4*)out + (size_t)blockIdx.y * T4;
    size_t stride = (size_t)gridDim.x * blockDim.x;
    for (size_t i = (size_t)blockIdx.x * blockDim.x + threadIdx.x; i < T4; i += stride)
        dst[i] = src[i];
}

// Gather the 2560 touched rows of each table into workspace; zero inverse counters.
__global__ void k_gather(const int* __restrict__ nodes,
                         const float* __restrict__ uw,
                         const float* __restrict__ vw,
                         float* __restrict__ eu,
                         float* __restrict__ ev,
                         int* __restrict__ cnt) {
    int p = blockIdx.x;
    int d = threadIdx.x;
    int node = nodes[p];
    eu[p * DIM + d] = uw[(size_t)node * DIM + d];
    ev[p * DIM + d] = vw[(size_t)node * DIM + d];
    if (d == 0) cnt[p] = 0;
}

// Build inverse index of idx_negv: for each position p, list of pair ids m with negv[m]==p.
__global__ void k_inv(const int* __restrict__ negv,
                      int* __restrict__ cnt,
                      int* __restrict__ inv) {
    int m = blockIdx.x * blockDim.x + threadIdx.x;
    if (m >= NNEG) return;
    int p = negv[m];
    int slot = atomicAdd(&cnt[p], 1);
    inv[p * INV_STRIDE + slot] = m;
}

// One wave per node position p: compute full grad_u[p], grad_v[p] in registers,
// then atomically apply LR*grad into the (already copied) output tables.
__global__ void __launch_bounds__(256) k_grad(
        const int*   __restrict__ nodes,
        const float* __restrict__ table,
        const int*   __restrict__ negu,
        const int*   __restrict__ negv,
        const float* __restrict__ eu,
        const float* __restrict__ ev,
        const int*   __restrict__ cnt,
        const int*   __restrict__ inv,
        float*       __restrict__ out) {
    int wid  = blockIdx.x * 4 + (threadIdx.x >> 6);
    int lane = threadIdx.x & 63;
    if (wid >= NPOSIT) return;
    int p = wid;
    int b = p / WALK;
    int i = p - b * WALK;

    const float4 mu = *(const float4*)&eu[p * DIM + lane * 4];
    const float4 mv = *(const float4*)&ev[p * DIM + lane * 4];

    float gux = 0.f, guy = 0.f, guz = 0.f, guw = 0.f;
    float gvx = 0.f, gvy = 0.f, gvz = 0.f, gvw = 0.f;

    // ---- positive pairs (window is symmetric, computed analytically) ----
    int jlo = (i - WIN < 0) ? 0 : i - WIN;
    int jhi = (i + WIN > WALK - 1) ? WALK - 1 : i + WIN;
    for (int j = jlo; j <= jhi; ++j) {
        if (j == i) continue;
        int q = b * WALK + j;
        float4 qu = *(const float4*)&eu[q * DIM + lane * 4];
        float4 qv = *(const float4*)&ev[q * DIM + lane * 4];

        // pair (u=p, v=q): contributes to grad_u[p]
        float d1 = wave_sum(mu.x * qv.x + mu.y * qv.y + mu.z * qv.z + mu.w * qv.w);
        float s1 = 1.0f - fast_sig(table, d1);
        gux += s1 * qv.x + LAP * (qv.x - mu.x);
        guy += s1 * qv.y + LAP * (qv.y - mu.y);
        guz += s1 * qv.z + LAP * (qv.z - mu.z);
        guw += s1 * qv.w + LAP * (qv.w - mu.w);

        // pair (u=q, v=p): contributes to grad_v[p]
        float d2 = wave_sum(qu.x * mv.x + qu.y * mv.y + qu.z * mv.z + qu.w * mv.w);
        float s2 = 1.0f - fast_sig(table, d2);
        gvx += s2 * qu.x + LAP * (qu.x - mv.x);
        gvy += s2 * qu.y + LAP * (qu.y - mv.y);
        gvz += s2 * qu.z + LAP * (qu.z - mv.z);
        gvw += s2 * qu.w + LAP * (qu.w - mv.w);
    }

    // ---- negatives where p is the center (u side): contiguous run in negv ----
    int S = 0;
    for (int k = 0; k < i; ++k)
        S += (k < WIN ? k : WIN) + ((WALK - 1 - k) < WIN ? (WALK - 1 - k) : WIN);
    int ci = (i < WIN ? i : WIN) + ((WALK - 1 - i) < WIN ? (WALK - 1 - i) : WIN);
    int mstart = 5 * (PPW * b + S);
    int mcnt   = 5 * ci;
    for (int t = 0; t < mcnt; ++t) {
        int z = negv[mstart + t];
        float4 zv = *(const float4*)&ev[z * DIM + lane * 4];
        float d  = wave_sum(mu.x * zv.x + mu.y * zv.y + mu.z * zv.z + mu.w * zv.w);
        float ns = -fast_sig(table, d);
        gux += ns * zv.x; guy += ns * zv.y; guz += ns * zv.z; guw += ns * zv.w;
    }

    // ---- negatives where p is the v side: via inverse index ----
    int ninv = cnt[p];
    for (int t = 0; t < ninv; ++t) {
        int m = inv[p * INV_STRIDE + t];
        int a = negu[m];
        float4 au = *(const float4*)&eu[a * DIM + lane * 4];
        float d  = wave_sum(au.x * mv.x + au.y * mv.y + au.z * mv.z + au.w * mv.w);
        float ns = -fast_sig(table, d);
        gvx += ns * au.x; gvy += ns * au.y; gvz += ns * au.z; gvw += ns * au.w;
    }

    // ---- apply LR*grad to output tables (atomic: flat may contain duplicates) ----
    int node = nodes[p];
    float* ou = out + (size_t)node * DIM + lane * 4;
    float* ov = out + ((size_t)EMB + (size_t)node) * DIM + lane * 4;
    atomicAdd(ou + 0, LR * gux);
    atomicAdd(ou + 1, LR * guy);
    atomicAdd(ou + 2, LR * guz);
    atomicAdd(ou + 3, LR * guw);
    atomicAdd(ov + 0, LR * gvx);
    atomicAdd(ov + 1, LR * gvy);
    atomicAdd(ov + 2, LR * gvz);
    atomicAdd(ov + 3, LR * gvw);
}

extern "C" void kernel_launch(void* const* d_in, const int* in_sizes, int n_in,
                              void* d_out, int out_size, void* d_ws, size_t ws_size,
                              hipStream_t stream) {
    const int*   nodes = (const int*)d_in[0];
    const float* uw    = (const float*)d_in[1];
    const float* vw    = (const float*)d_in[2];
    const float* table = (const float*)d_in[3];
    // d_in[4] = idx_posu, d_in[5] = idx_posv (not needed: window is analytic)
    const int*   negu  = (const int*)d_in[6];
    const int*   negv  = (const int*)d_in[7];
    float* out = (float*)d_out;

    float* eu  = (float*)d_ws;
    float* ev  = eu + (size_t)NPOSIT * DIM;
    int*   cnt = (int*)(ev + (size_t)NPOSIT * DIM);
    int*   inv = cnt + NPOSIT;

    // Cheap prep first (grad inputs), then the big copy, then grad (atomics on
    // freshly-copied, L2-resident rows).
    k_gather<<<NPOSIT, DIM, 0, stream>>>(nodes, uw, vw, eu, ev, cnt);
    k_inv<<<(NNEG + 255) / 256, 256, 0, stream>>>(negv, cnt, inv);

    dim3 cgrid(2048, 2);
    k_copy<<<cgrid, 256, 0, stream>>>(uw, vw, out);

    k_grad<<<NPOSIT / 4, 256, 0, stream>>>(nodes, table, negu, negv, eu, ev, cnt, inv, out);
}

// Round 3
// 214.802 us; speedup vs baseline: 1.3536x; 1.3536x over previous
//
#include <hip/hip_runtime.h>

// Problem constants (mirror the reference)
#define EMB      200000
#define DIM      256
#define WALK     80
#define WIN      5
#define BATCH    32
#define PPW      770                 // positive pairs per walk: sum_i c(i)
#define NPOSN    (BATCH * PPW)       // 24640 positive pairs
#define NNEG     (NPOSN * 5)         // 123200 negative pairs
#define NPOSIT   (BATCH * WALK)      // 2560 node positions
#define LR       0.025f
#define LAP      0.01f
#define INV_STRIDE 64                // max 50 inverse hits per position

#define GRAD_BLOCKS 1280             // 5120 waves: u-side then v-side per position
#define COPY_BLOCKS 2048             // 1024 per table

__device__ __forceinline__ float wave_sum(float s) {
#pragma unroll
    for (int off = 32; off > 0; off >>= 1) s += __shfl_xor(s, off, 64);
    return s;
}

__device__ __forceinline__ float fast_sig(const float* __restrict__ t, float d) {
    float s = fminf(fmaxf(d, -6.0f), 6.0f);
    int idx = (int)floorf((s + 6.01f) / 0.01f);
    return t[idx];
}

// Gather the 2560 touched rows of each table into workspace; zero inverse counters.
__global__ void k_gather(const int* __restrict__ nodes,
                         const float* __restrict__ uw,
                         const float* __restrict__ vw,
                         float* __restrict__ eu,
                         float* __restrict__ ev,
                         int* __restrict__ cnt) {
    int p = blockIdx.x;
    int d = threadIdx.x;
    int node = nodes[p];
    eu[p * DIM + d] = uw[(size_t)node * DIM + d];
    ev[p * DIM + d] = vw[(size_t)node * DIM + d];
    if (d == 0) cnt[p] = 0;
}

// Build inverse index of idx_negv: for each position p, list of pair ids m with negv[m]==p.
__global__ void k_inv(const int* __restrict__ negv,
                      int* __restrict__ cnt,
                      int* __restrict__ inv) {
    int m = blockIdx.x * blockDim.x + threadIdx.x;
    if (m >= NNEG) return;
    int p = negv[m];
    int slot = atomicAdd(&cnt[p], 1);
    inv[p * INV_STRIDE + slot] = m;
}

// Fused kernel:
//   blocks [0, GRAD_BLOCKS)             : gradient compute into gu/gv (ws only)
//   blocks [GRAD_BLOCKS, +COPY_BLOCKS)  : 819 MB table copy into out
// The grad work is VALU/latency-bound and hides entirely under the HBM-bound copy.
__global__ void __launch_bounds__(256) k_fused(
        const float* __restrict__ uw,
        const float* __restrict__ vw,
        const float* __restrict__ table,
        const int*   __restrict__ negu,
        const int*   __restrict__ negv,
        const float* __restrict__ eu,
        const float* __restrict__ ev,
        const int*   __restrict__ cnt,
        const int*   __restrict__ inv,
        float*       __restrict__ gu,
        float*       __restrict__ gv,
        float*       __restrict__ out) {
    if (blockIdx.x >= GRAD_BLOCKS) {
        // ---------------- copy half ----------------
        const size_t T4 = (size_t)EMB * DIM / 4;       // float4 per table
        int cb  = blockIdx.x - GRAD_BLOCKS;            // 0..2047
        int tbl = cb & 1;
        int blk = cb >> 1;                             // 0..1023
        const float4* __restrict__ src = tbl ? (const float4*)vw : (const float4*)uw;
        float4* __restrict__ dst = (float4*)out + (size_t)tbl * T4;
        const size_t stride = (size_t)(COPY_BLOCKS / 2) * 256;
        for (size_t i = (size_t)blk * 256 + threadIdx.x; i < T4; i += stride)
            dst[i] = src[i];
        return;
    }

    // ---------------- grad half ----------------
    int wid  = blockIdx.x * 4 + (threadIdx.x >> 6);    // 0..5119
    int lane = threadIdx.x & 63;
    int side = wid >= NPOSIT;                          // 0: u-side, 1: v-side
    int p    = side ? wid - NPOSIT : wid;
    int b    = p / WALK;
    int i    = p - b * WALK;

    int jlo = (i - WIN < 0) ? 0 : i - WIN;
    int jhi = (i + WIN > WALK - 1) ? WALK - 1 : i + WIN;

    if (!side) {
        // grad_u[p]: pairs (u=p, v=q) over window + negatives where p is center.
        const float4 mu = *(const float4*)&eu[p * DIM + lane * 4];
        float gx = 0.f, gy = 0.f, gz = 0.f, gw = 0.f;

        for (int j = jlo; j <= jhi; ++j) {
            if (j == i) continue;
            int q = b * WALK + j;
            float4 qv = *(const float4*)&ev[q * DIM + lane * 4];
            float d1 = wave_sum(mu.x * qv.x + mu.y * qv.y + mu.z * qv.z + mu.w * qv.w);
            float s1 = 1.0f - fast_sig(table, d1);
            gx += s1 * qv.x + LAP * (qv.x - mu.x);
            gy += s1 * qv.y + LAP * (qv.y - mu.y);
            gz += s1 * qv.z + LAP * (qv.z - mu.z);
            gw += s1 * qv.w + LAP * (qv.w - mu.w);
        }

        int S = 0;
        for (int k = 0; k < i; ++k)
            S += (k < WIN ? k : WIN) + ((WALK - 1 - k) < WIN ? (WALK - 1 - k) : WIN);
        int ci = (i < WIN ? i : WIN) + ((WALK - 1 - i) < WIN ? (WALK - 1 - i) : WIN);
        int mstart = 5 * (PPW * b + S);
        int mcnt   = 5 * ci;
        for (int t = 0; t < mcnt; ++t) {
            int z = negv[mstart + t];
            float4 zv = *(const float4*)&ev[z * DIM + lane * 4];
            float d  = wave_sum(mu.x * zv.x + mu.y * zv.y + mu.z * zv.z + mu.w * zv.w);
            float ns = -fast_sig(table, d);
            gx += ns * zv.x; gy += ns * zv.y; gz += ns * zv.z; gw += ns * zv.w;
        }
        *(float4*)&gu[p * DIM + lane * 4] = make_float4(gx, gy, gz, gw);
    } else {
        // grad_v[p]: pairs (u=q, v=p) over window + negatives where p is the v target.
        const float4 mv = *(const float4*)&ev[p * DIM + lane * 4];
        float gx = 0.f, gy = 0.f, gz = 0.f, gw = 0.f;

        for (int j = jlo; j <= jhi; ++j) {
            if (j == i) continue;
            int q = b * WALK + j;
            float4 qu = *(const float4*)&eu[q * DIM + lane * 4];
            float d2 = wave_sum(qu.x * mv.x + qu.y * mv.y + qu.z * mv.z + qu.w * mv.w);
            float s2 = 1.0f - fast_sig(table, d2);
            gx += s2 * qu.x + LAP * (qu.x - mv.x);
            gy += s2 * qu.y + LAP * (qu.y - mv.y);
            gz += s2 * qu.z + LAP * (qu.z - mv.z);
            gw += s2 * qu.w + LAP * (qu.w - mv.w);
        }

        int ninv = cnt[p];
        for (int t = 0; t < ninv; ++t) {
            int m = inv[p * INV_STRIDE + t];
            int a = negu[m];
            float4 au = *(const float4*)&eu[a * DIM + lane * 4];
            float d  = wave_sum(au.x * mv.x + au.y * mv.y + au.z * mv.z + au.w * mv.w);
            float ns = -fast_sig(table, d);
            gx += ns * au.x; gy += ns * au.y; gz += ns * au.z; gw += ns * au.w;
        }
        *(float4*)&gv[p * DIM + lane * 4] = make_float4(gx, gy, gz, gw);
    }
}

// Apply LR*grad into the copied output tables (atomic: flat may contain duplicate nodes).
__global__ void k_apply(const int* __restrict__ nodes,
                        const float* __restrict__ gu,
                        const float* __restrict__ gv,
                        float* __restrict__ out) {
    int p = blockIdx.x;
    int d = threadIdx.x;
    int node = nodes[p];
    atomicAdd(&out[(size_t)node * DIM + d],               LR * gu[p * DIM + d]);
    atomicAdd(&out[((size_t)EMB + (size_t)node) * DIM + d], LR * gv[p * DIM + d]);
}

extern "C" void kernel_launch(void* const* d_in, const int* in_sizes, int n_in,
                              void* d_out, int out_size, void* d_ws, size_t ws_size,
                              hipStream_t stream) {
    const int*   nodes = (const int*)d_in[0];
    const float* uw    = (const float*)d_in[1];
    const float* vw    = (const float*)d_in[2];
    const float* table = (const float*)d_in[3];
    // d_in[4] = idx_posu, d_in[5] = idx_posv (not needed: window is analytic)
    const int*   negu  = (const int*)d_in[6];
    const int*   negv  = (const int*)d_in[7];
    float* out = (float*)d_out;

    float* eu  = (float*)d_ws;
    float* ev  = eu + (size_t)NPOSIT * DIM;
    float* gu  = ev + (size_t)NPOSIT * DIM;
    float* gv  = gu + (size_t)NPOSIT * DIM;
    int*   cnt = (int*)(gv + (size_t)NPOSIT * DIM);
    int*   inv = cnt + NPOSIT;

    // 1. Gather touched rows + zero counters.
    k_gather<<<NPOSIT, DIM, 0, stream>>>(nodes, uw, vw, eu, ev, cnt);
    // 2. Build inverse index of negv.
    k_inv<<<(NNEG + 255) / 256, 256, 0, stream>>>(negv, cnt, inv);
    // 3. Fused: grad compute (ws-only) overlapped with the 819 MB table copy.
    k_fused<<<GRAD_BLOCKS + COPY_BLOCKS, 256, 0, stream>>>(
        uw, vw, table, negu, negv, eu, ev, cnt, inv, gu, gv, out);
    // 4. Scatter LR*grad into out (handles duplicate node ids).
    k_apply<<<NPOSIT, DIM, 0, stream>>>(nodes, gu, gv, out);
}